// Round 3
// baseline (1246.764 us; speedup 1.0000x reference)
//
#include <hip/hip_runtime.h>
#include <hip/hip_bf16.h>
#include <stdint.h>

#define DEVINL __device__ __forceinline__

typedef unsigned short u16;
typedef unsigned int   u32;
typedef unsigned long long u64;

using short8 = __attribute__((ext_vector_type(8))) short;
using f32x4  = __attribute__((ext_vector_type(4))) float;

DEVINL u16 f2bf(float f) {                       // RNE float->bf16
  u32 u = __builtin_bit_cast(u32, f);
  return (u16)((u + 0x7fffu + ((u >> 16) & 1u)) >> 16);
}
DEVINL float bf2f(u16 v) { return __builtin_bit_cast(float, ((u32)v) << 16); }

typedef const unsigned int __attribute__((address_space(1)))* gas1_t;
typedef unsigned int __attribute__((address_space(3)))* las3_t;

DEVINL void gl_lds16(const void* g, void* l) {   // async global->LDS, 16B/lane
  __builtin_amdgcn_global_load_lds((gas1_t)(uintptr_t)g, (las3_t)(uintptr_t)l, 16, 0, 0);
}

// ---------------- elementwise converts ----------------
__global__ void cvt_bf16_kernel(const float* __restrict__ s, u16* __restrict__ d, int n4) {
  int i = blockIdx.x * 256 + threadIdx.x;
  if (i >= n4) return;
  float4 v = ((const float4*)s)[i];
  u32 lo = (u32)f2bf(v.x) | ((u32)f2bf(v.y) << 16);
  u32 hi = (u32)f2bf(v.z) | ((u32)f2bf(v.w) << 16);
  ((uint2*)d)[i] = make_uint2(lo, hi);
}

__global__ void build_combined_kernel(const float* __restrict__ f1,
                                      const float* __restrict__ f2,
                                      u16* __restrict__ d) {
  int i = blockIdx.x * 256 + threadIdx.x;        // 8192*2048/4 groups, grid exact
  int row = i >> 9, c4 = i & 511;                // 512 float4-groups per row
  const float* s = (c4 < 256) ? (f1 + (size_t)row * 1024 + c4 * 4)
                              : (f2 + (size_t)row * 1024 + (c4 - 256) * 4);
  float4 v = *(const float4*)s;
  u32 lo = (u32)f2bf(v.x) | ((u32)f2bf(v.y) << 16);
  u32 hi = (u32)f2bf(v.z) | ((u32)f2bf(v.w) << 16);
  ((uint2*)d)[i] = make_uint2(lo, hi);
}

// ---------------- fused KAN GEMM ----------------
// C[m,n] = sum_k A[m,k] * W[n,k]   (W row-major N x K, bf16)
// SPLINE: A staged as on-the-fly cubic B-spline bases of x (K = 8 * x_cols)
// EPI: 0=attention(sigmoid+gate+silu outs) 1=store f32 2=add+h/silu(h) bf16 3=add into outf
constexpr int BM = 128, BK = 64;

template <int BN, bool SPLINE, int EPI>
__global__ __launch_bounds__((BN == 256) ? 512 : 256)
void kan_gemm(const u16* __restrict__ Asrc, const u16* __restrict__ Bw,
              int K, int lda,
              const float* __restrict__ bias,
              const float* __restrict__ f1g, const float* __restrict__ f2g,
              u16* __restrict__ o_a, u16* __restrict__ o_b,
              const float* addsrc, float* outf) {
  constexpr int THREADS = (BN == 256) ? 512 : 256;
  constexpr int WN = BN / 64;
  constexpr int AR = (BM * BK) / (THREADS * 8);  // A staging rounds (8 elems = 16B / thread)
  constexpr int BR = (BN * BK) / (THREADS * 8);

  __shared__ __align__(16) u16 As[BM * BK];
  __shared__ __align__(16) u16 Bs[BN * BK];

  const int tid = threadIdx.x;
  const int lane = tid & 63;
  const int wv = tid >> 6;
  const int wm = wv / WN, wn = wv % WN;
  const int l15 = lane & 15, lhi = lane >> 4;
  const int m0 = blockIdx.x * BM, n0 = blockIdx.y * BN;

  f32x4 acc[4][4] = {};

  for (int kt = 0; kt < K; kt += BK) {
    // ---- stage A tile ----
    if constexpr (!SPLINE) {
#pragma unroll
      for (int r = 0; r < AR; ++r) {
        int e = (r * THREADS + tid) * 8;
        int row = e >> 6, col = e & 63;
        gl_lds16(Asrc + (size_t)(m0 + row) * lda + kt + col, &As[e]);
      }
    } else {
      // each thread produces bases for (BM*8)/THREADS x-values (8 bf16 each -> 16B LDS)
#pragma unroll
      for (int s = 0; s < (BM * 8) / THREADS; ++s) {
        int e = tid + s * THREADS;
        int row = e >> 3, xc = e & 7;
        float xv = bf2f(Asrc[(size_t)(m0 + row) * lda + (kt >> 3) + xc]);
        // u = (x + 2.2)/0.4 ; interval p = floor(u); local t = frac(u)
        float uu = fmaf(xv, 2.5f, 5.5f);
        float fl = floorf(uu);
        int p = (int)fl;
        float t = uu - fl;
        bool valid = (uu >= 0.0f) && (uu < 11.0f);
        float t2 = t * t, t3 = t2 * t;
        float s1 = 1.0f - t;
        float v0 = t3 * (1.0f / 6.0f);                                        // slot p
        float v1 = fmaf(t3, -0.5f, fmaf(t2, 0.5f, fmaf(t, 0.5f, 1.0f / 6.0f))); // p-1
        float v2 = fmaf(t3, 0.5f, fmaf(t2, -1.0f, 2.0f / 3.0f));              // p-2
        float v3 = s1 * s1 * s1 * (1.0f / 6.0f);                              // p-3
        u64 wp = (u64)f2bf(v3) | ((u64)f2bf(v2) << 16) |
                 ((u64)f2bf(v1) << 32) | ((u64)f2bf(v0) << 48);
        if (!valid) wp = 0;
        int pcl = p < 0 ? 0 : (p > 10 ? 10 : p);
        int sb = (pcl << 4) - 48;                 // bit-position of window start
        u32 wd[4];
#pragma unroll
        for (int wi = 0; wi < 4; ++wi) {
          int dd = 32 * wi - sb;
          u32 val = 0;
          if (dd > -32 && dd < 64)
            val = (dd >= 0) ? (u32)(wp >> dd) : (u32)(wp << (-dd));
          wd[wi] = val;
        }
        *(uint4*)&As[(row << 6) + (xc << 3)] = make_uint4(wd[0], wd[1], wd[2], wd[3]);
      }
    }
    // ---- stage B tile ----
#pragma unroll
    for (int r = 0; r < BR; ++r) {
      int e = (r * THREADS + tid) * 8;
      int row = e >> 6, col = e & 63;
      gl_lds16(Bw + (size_t)(n0 + row) * K + kt + col, &Bs[e]);
    }
    __syncthreads();
    // ---- MFMA ----
#pragma unroll
    for (int ks = 0; ks < BK; ks += 32) {
      short8 av[4], bv[4];
#pragma unroll
      for (int i = 0; i < 4; ++i)
        av[i] = *(const short8*)&As[(wm * 64 + i * 16 + l15) * BK + ks + lhi * 8];
#pragma unroll
      for (int j = 0; j < 4; ++j)
        bv[j] = *(const short8*)&Bs[(wn * 64 + j * 16 + l15) * BK + ks + lhi * 8];
#pragma unroll
      for (int i = 0; i < 4; ++i)
#pragma unroll
        for (int j = 0; j < 4; ++j)
          acc[i][j] = __builtin_amdgcn_mfma_f32_16x16x32_bf16(av[i], bv[j], acc[i][j], 0, 0, 0);
    }
    __syncthreads();
  }

  // ---- epilogue ----  C/D layout: col = lane&15, row = (lane>>4)*4 + reg   [m89/m91]
  const int rbase = m0 + wm * 64 + lhi * 4;
  const int cbase = n0 + wn * 64 + l15;
#pragma unroll
  for (int i = 0; i < 4; ++i) {
#pragma unroll
    for (int r = 0; r < 4; ++r) {
      const int grow = rbase + i * 16 + r;
#pragma unroll
      for (int j = 0; j < 4; ++j) {
        const int gcol = cbase + j * 16;
        float v = acc[i][j][r];
        if constexpr (EPI == 0) {
          float att = 1.0f / (1.0f + __expf(-(v + bias[gcol])));
          float a1 = f1g[(size_t)grow * 1024 + gcol] * att;
          float a2 = f2g[(size_t)grow * 1024 + gcol] * (1.0f - att);
          size_t b0i = (size_t)grow * 2048 + gcol;
          o_a[b0i]        = f2bf(a1);                               // kan_in
          o_a[b0i + 1024] = f2bf(a2);
          o_b[b0i]        = f2bf(a1 / (1.0f + __expf(-a1)));        // silu(kan_in)
          o_b[b0i + 1024] = f2bf(a2 / (1.0f + __expf(-a2)));
        } else if constexpr (EPI == 1) {
          outf[(size_t)grow * 1024 + gcol] = v;
        } else if constexpr (EPI == 2) {
          size_t ix = (size_t)grow * 1024 + gcol;
          float h = v + addsrc[ix];
          o_a[ix] = f2bf(h);                                        // h (bf16)
          o_b[ix] = f2bf(h / (1.0f + __expf(-h)));                  // silu(h)
        } else {
          size_t ix = (size_t)grow * 1024 + gcol;
          outf[ix] = v + addsrc[ix];
        }
      }
    }
  }
}

// ---------------- host launch ----------------
extern "C" void kernel_launch(void* const* d_in, const int* in_sizes, int n_in,
                              void* d_out, int out_size, void* d_ws, size_t ws_size,
                              hipStream_t stream) {
  const float* feat1     = (const float*)d_in[0];
  const float* feat2     = (const float*)d_in[1];
  const float* attn_w    = (const float*)d_in[2];
  const float* attn_b    = (const float*)d_in[3];
  const float* base_w0   = (const float*)d_in[4];
  const float* spline_w0 = (const float*)d_in[5];
  const float* base_w1   = (const float*)d_in[6];
  const float* spline_w1 = (const float*)d_in[7];
  float* out = (float*)d_out;
  char*  ws  = (char*)d_ws;

  // workspace layout (168 MiB total)
  u16* attn_w_bf    = (u16*)(ws + 0);                       //  4 MiB
  u16* base_w0_bf   = (u16*)(ws + 4194304);                 //  4 MiB
  u16* spline_w0_bf = (u16*)(ws + 8388608);                 // 32 MiB
  u16* combined     = (u16*)(ws + 41943040);                // 32 MiB (reused below)
  u16* h_bf         = combined;                             // 16 MiB (after attn GEMM)
  u16* silu1        = (u16*)(ws + 41943040 + 16777216);     // 16 MiB
  u16* x0           = (u16*)(ws + 75497472);                // 32 MiB (reused below)
  u16* base_w1_bf   = x0;                                   //  2 MiB (after spline0)
  u16* spline_w1_bf = (u16*)(ws + 75497472 + 2097152);      // 16 MiB
  u16* silu0        = (u16*)(ws + 109051904);               // 32 MiB
  float* h32        = (float*)(ws + 142606336);             // 32 MiB

  auto cvt = [&](const float* s, u16* d, int n) {
    int n4 = n >> 2;
    cvt_bf16_kernel<<<(n4 + 255) / 256, 256, 0, stream>>>(s, d, n4);
  };

  cvt(attn_w, attn_w_bf, 1024 * 2048);
  cvt(base_w0, base_w0_bf, 1024 * 2048);
  cvt(spline_w0, spline_w0_bf, 1024 * 2048 * 8);
  build_combined_kernel<<<16384, 256, 0, stream>>>(feat1, feat2, combined);

  dim3 g128(8192 / 128, 1024 / 128);
  dim3 g256(8192 / 128, 1024 / 256);

  // attention = sigmoid(combined @ attn_w^T + b); epilogue emits kan_in + silu(kan_in)
  kan_gemm<128, false, 0><<<g128, 256, 0, stream>>>(
      combined, attn_w_bf, 2048, 2048, attn_b, feat1, feat2, x0, silu0, nullptr, nullptr);
  // base0: h32 = silu0 @ base_w0^T
  kan_gemm<128, false, 1><<<g128, 256, 0, stream>>>(
      silu0, base_w0_bf, 2048, 2048, nullptr, nullptr, nullptr, nullptr, nullptr, nullptr, h32);
  // spline0: h = h32 + bases(x0) @ spline_w0^T ; emit h_bf + silu1
  kan_gemm<256, true, 2><<<g256, 512, 0, stream>>>(
      x0, spline_w0_bf, 16384, 2048, nullptr, nullptr, nullptr, h_bf, silu1, h32, nullptr);
  // layer-1 weights (into dead x0 region)
  cvt(base_w1, base_w1_bf, 1024 * 1024);
  cvt(spline_w1, spline_w1_bf, 1024 * 1024 * 8);
  // base1: out = silu1 @ base_w1^T
  kan_gemm<128, false, 1><<<g128, 256, 0, stream>>>(
      silu1, base_w1_bf, 1024, 1024, nullptr, nullptr, nullptr, nullptr, nullptr, nullptr, out);
  // spline1: out += bases(h_bf) @ spline_w1^T
  kan_gemm<256, true, 3><<<g256, 512, 0, stream>>>(
      h_bf, spline_w1_bf, 8192, 1024, nullptr, nullptr, nullptr, nullptr, nullptr, out, out);
}

// Round 4
// 1244.713 us; speedup vs baseline: 1.0016x; 1.0016x over previous
//
#include <hip/hip_runtime.h>
#include <hip/hip_bf16.h>
#include <stdint.h>

#define DEVINL __device__ __forceinline__

typedef unsigned short u16;
typedef unsigned int   u32;
typedef unsigned long long u64;

using short8 = __attribute__((ext_vector_type(8))) short;
using f32x4  = __attribute__((ext_vector_type(4))) float;

DEVINL u16 f2bf(float f) {                       // RNE float->bf16
  u32 u = __builtin_bit_cast(u32, f);
  return (u16)((u + 0x7fffu + ((u >> 16) & 1u)) >> 16);
}
DEVINL float bf2f(u16 v) { return __builtin_bit_cast(float, ((u32)v) << 16); }

typedef const unsigned int __attribute__((address_space(1)))* gas1_t;
typedef unsigned int __attribute__((address_space(3)))* las3_t;

DEVINL void gl_lds16(const void* g, void* l) {   // async global->LDS, 16B/lane
  __builtin_amdgcn_global_load_lds((gas1_t)(uintptr_t)g, (las3_t)(uintptr_t)l, 16, 0, 0);
}

// ---- uniform cubic B-spline: 8 bases (bf16) of one x, packed as uint4 ----
DEVINL uint4 bspline8(float xv) {
  float uu = fmaf(xv, 2.5f, 5.5f);               // u = (x + 2.2)/0.4
  float fl = floorf(uu);
  int p = (int)fl;
  float t = uu - fl;
  bool valid = (uu >= 0.0f) && (uu < 11.0f);
  float t2 = t * t, t3 = t2 * t;
  float s1 = 1.0f - t;
  float v0 = t3 * (1.0f / 6.0f);                                          // slot p
  float v1 = fmaf(t3, -0.5f, fmaf(t2, 0.5f, fmaf(t, 0.5f, 1.0f / 6.0f))); // p-1
  float v2 = fmaf(t3, 0.5f, fmaf(t2, -1.0f, 2.0f / 3.0f));                // p-2
  float v3 = s1 * s1 * s1 * (1.0f / 6.0f);                                // p-3
  u64 wp = (u64)f2bf(v3) | ((u64)f2bf(v2) << 16) |
           ((u64)f2bf(v1) << 32) | ((u64)f2bf(v0) << 48);
  if (!valid) wp = 0;
  int pcl = p < 0 ? 0 : (p > 10 ? 10 : p);
  int sb = (pcl << 4) - 48;                      // bit-position of window start
  u32 wd[4];
#pragma unroll
  for (int wi = 0; wi < 4; ++wi) {
    int dd = 32 * wi - sb;
    u32 val = 0;
    if (dd > -32 && dd < 64)
      val = (dd >= 0) ? (u32)(wp >> dd) : (u32)(wp << (-dd));
    wd[wi] = val;
  }
  return make_uint4(wd[0], wd[1], wd[2], wd[3]);
}

// ---------------- elementwise kernels ----------------
__global__ void cvt_bf16_kernel(const float* __restrict__ s, u16* __restrict__ d, int n4) {
  int i = blockIdx.x * 256 + threadIdx.x;
  if (i >= n4) return;
  float4 v = ((const float4*)s)[i];
  u32 lo = (u32)f2bf(v.x) | ((u32)f2bf(v.y) << 16);
  u32 hi = (u32)f2bf(v.z) | ((u32)f2bf(v.w) << 16);
  ((uint2*)d)[i] = make_uint2(lo, hi);
}

__global__ void build_combined_kernel(const float* __restrict__ f1,
                                      const float* __restrict__ f2,
                                      u16* __restrict__ d) {
  int i = blockIdx.x * 256 + threadIdx.x;        // 8192*2048/4 groups, grid exact
  int row = i >> 9, c4 = i & 511;                // 512 float4-groups per row
  const float* s = (c4 < 256) ? (f1 + (size_t)row * 1024 + c4 * 4)
                              : (f2 + (size_t)row * 1024 + (c4 - 256) * 4);
  float4 v = *(const float4*)s;
  u32 lo = (u32)f2bf(v.x) | ((u32)f2bf(v.y) << 16);
  u32 hi = (u32)f2bf(v.z) | ((u32)f2bf(v.w) << 16);
  ((uint2*)d)[i] = make_uint2(lo, hi);
}

// bases[f*8 .. f*8+7] = B_g(x_f) for flat x index f; thread handles 4 x (8B in, 64B out)
__global__ void basis_gen_kernel(const u16* __restrict__ x, u16* __restrict__ bases, int total4) {
  for (int i = blockIdx.x * 256 + threadIdx.x; i < total4; i += gridDim.x * 256) {
    uint2 xv = ((const uint2*)x)[i];
    u16 xs[4] = {(u16)(xv.x & 0xffff), (u16)(xv.x >> 16),
                 (u16)(xv.y & 0xffff), (u16)(xv.y >> 16)};
#pragma unroll
    for (int j = 0; j < 4; ++j)
      ((uint4*)bases)[(size_t)i * 4 + j] = bspline8(bf2f(xs[j]));
  }
}

// ---------------- fused KAN GEMM ----------------
// C[m,n] = sum_k A[m,k] * W[n,k]   (W row-major N x K, bf16)
// SPLINE: A staged as on-the-fly cubic B-spline bases of x (K = 8 * x_cols) [fallback path]
// EPI: 0=attention(sigmoid+gate+silu outs) 1=store f32 2=add+h/silu(h) bf16 3=add into outf
constexpr int BM = 128, BK = 64;

template <int BN, bool SPLINE, int EPI>
__global__ __launch_bounds__((BN == 256) ? 512 : 256)
void kan_gemm(const u16* __restrict__ Asrc, const u16* __restrict__ Bw,
              int K, int lda,
              const float* __restrict__ bias,
              const float* __restrict__ f1g, const float* __restrict__ f2g,
              u16* __restrict__ o_a, u16* __restrict__ o_b,
              const float* addsrc, float* outf) {
  constexpr int THREADS = (BN == 256) ? 512 : 256;
  constexpr int WN = BN / 64;
  constexpr int AR = (BM * BK) / (THREADS * 8);  // A staging rounds (8 elems = 16B / thread)
  constexpr int BR = (BN * BK) / (THREADS * 8);

  __shared__ __align__(16) u16 As[BM * BK];
  __shared__ __align__(16) u16 Bs[BN * BK];

  const int tid = threadIdx.x;
  const int lane = tid & 63;
  const int wv = tid >> 6;
  const int wm = wv / WN, wn = wv % WN;
  const int l15 = lane & 15, lhi = lane >> 4;
  const int m0 = blockIdx.x * BM, n0 = blockIdx.y * BN;

  f32x4 acc[4][4] = {};

  for (int kt = 0; kt < K; kt += BK) {
    // ---- stage A tile ----
    if constexpr (!SPLINE) {
#pragma unroll
      for (int r = 0; r < AR; ++r) {
        int e = (r * THREADS + tid) * 8;
        int row = e >> 6, col = e & 63;
        gl_lds16(Asrc + (size_t)(m0 + row) * lda + kt + col, &As[e]);
      }
    } else {
#pragma unroll
      for (int s = 0; s < (BM * 8) / THREADS; ++s) {
        int e = tid + s * THREADS;
        int row = e >> 3, xc = e & 7;
        float xv = bf2f(Asrc[(size_t)(m0 + row) * lda + (kt >> 3) + xc]);
        *(uint4*)&As[(row << 6) + (xc << 3)] = bspline8(xv);
      }
    }
    // ---- stage B tile ----
#pragma unroll
    for (int r = 0; r < BR; ++r) {
      int e = (r * THREADS + tid) * 8;
      int row = e >> 6, col = e & 63;
      gl_lds16(Bw + (size_t)(n0 + row) * K + kt + col, &Bs[e]);
    }
    __syncthreads();
    // ---- MFMA ----
#pragma unroll
    for (int ks = 0; ks < BK; ks += 32) {
      short8 av[4], bv[4];
#pragma unroll
      for (int i = 0; i < 4; ++i)
        av[i] = *(const short8*)&As[(wm * 64 + i * 16 + l15) * BK + ks + lhi * 8];
#pragma unroll
      for (int j = 0; j < 4; ++j)
        bv[j] = *(const short8*)&Bs[(wn * 64 + j * 16 + l15) * BK + ks + lhi * 8];
#pragma unroll
      for (int i = 0; i < 4; ++i)
#pragma unroll
        for (int j = 0; j < 4; ++j)
          acc[i][j] = __builtin_amdgcn_mfma_f32_16x16x32_bf16(av[i], bv[j], acc[i][j], 0, 0, 0);
    }
    __syncthreads();
  }

  // ---- epilogue ----  C/D layout: col = lane&15, row = (lane>>4)*4 + reg   [m89/m91]
  const int rbase = m0 + wm * 64 + lhi * 4;
  const int cbase = n0 + wn * 64 + l15;
#pragma unroll
  for (int i = 0; i < 4; ++i) {
#pragma unroll
    for (int r = 0; r < 4; ++r) {
      const int grow = rbase + i * 16 + r;
#pragma unroll
      for (int j = 0; j < 4; ++j) {
        const int gcol = cbase + j * 16;
        float v = acc[i][j][r];
        if constexpr (EPI == 0) {
          float att = 1.0f / (1.0f + __expf(-(v + bias[gcol])));
          float a1 = f1g[(size_t)grow * 1024 + gcol] * att;
          float a2 = f2g[(size_t)grow * 1024 + gcol] * (1.0f - att);
          size_t b0i = (size_t)grow * 2048 + gcol;
          o_a[b0i]        = f2bf(a1);                               // kan_in
          o_a[b0i + 1024] = f2bf(a2);
          o_b[b0i]        = f2bf(a1 / (1.0f + __expf(-a1)));        // silu(kan_in)
          o_b[b0i + 1024] = f2bf(a2 / (1.0f + __expf(-a2)));
        } else if constexpr (EPI == 1) {
          outf[(size_t)grow * 1024 + gcol] = v;
        } else if constexpr (EPI == 2) {
          size_t ix = (size_t)grow * 1024 + gcol;
          float h = v + addsrc[ix];
          o_a[ix] = f2bf(h);                                        // h (bf16)
          o_b[ix] = f2bf(h / (1.0f + __expf(-h)));                  // silu(h)
        } else {
          size_t ix = (size_t)grow * 1024 + gcol;
          outf[ix] = v + addsrc[ix];
        }
      }
    }
  }
}

// ---------------- host launch ----------------
extern "C" void kernel_launch(void* const* d_in, const int* in_sizes, int n_in,
                              void* d_out, int out_size, void* d_ws, size_t ws_size,
                              hipStream_t stream) {
  const float* feat1     = (const float*)d_in[0];
  const float* feat2     = (const float*)d_in[1];
  const float* attn_w    = (const float*)d_in[2];
  const float* attn_b    = (const float*)d_in[3];
  const float* base_w0   = (const float*)d_in[4];
  const float* spline_w0 = (const float*)d_in[5];
  const float* base_w1   = (const float*)d_in[6];
  const float* spline_w1 = (const float*)d_in[7];
  float* out = (float*)d_out;
  char*  ws  = (char*)d_ws;
  const size_t MB = 1048576ull;

  auto cvt = [&](const float* s, u16* d, int n) {
    int n4 = n >> 2;
    cvt_bf16_kernel<<<(n4 + 255) / 256, 256, 0, stream>>>(s, d, n4);
  };

  dim3 g128(8192 / 128, 1024 / 128);

  if (ws_size >= 442 * MB) {
    // ---------- primary path: precomputed basis buffer ----------
    u16* attn_w_bf    = (u16*)(ws + 0 * MB);      //  4 MiB
    u16* base_w0_bf   = (u16*)(ws + 4 * MB);      //  4 MiB
    u16* spline_w0_bf = (u16*)(ws + 8 * MB);      // 32 MiB
    u16* base_w1_bf   = (u16*)(ws + 40 * MB);     //  2 MiB
    u16* spline_w1_bf = (u16*)(ws + 42 * MB);     // 16 MiB
    u16* combined     = (u16*)(ws + 58 * MB);     // 32 MiB; h_bf overlays (16 MiB)
    u16* h_bf         = combined;
    u16* x0           = (u16*)(ws + 90 * MB);     // 32 MiB (dead after basis0)
    u16* silu0        = (u16*)(ws + 122 * MB);    // 32 MiB; silu1 overlays (16 MiB)
    u16* silu1        = silu0;
    float* h32        = (float*)(ws + 154 * MB);  // 32 MiB
    u16* bases        = (u16*)(ws + 186 * MB);    // 256 MiB (bases0; bases1 overlays)

    cvt(attn_w, attn_w_bf, 1024 * 2048);
    cvt(base_w0, base_w0_bf, 1024 * 2048);
    cvt(spline_w0, spline_w0_bf, 1024 * 2048 * 8);
    cvt(base_w1, base_w1_bf, 1024 * 1024);
    cvt(spline_w1, spline_w1_bf, 1024 * 1024 * 8);
    build_combined_kernel<<<16384, 256, 0, stream>>>(feat1, feat2, combined);

    // attention: epilogue emits kan_in (x0) + silu(kan_in) (silu0)
    kan_gemm<128, false, 0><<<g128, 256, 0, stream>>>(
        combined, attn_w_bf, 2048, 2048, attn_b, feat1, feat2, x0, silu0, nullptr, nullptr);
    // bases of layer-0 x
    basis_gen_kernel<<<2048, 256, 0, stream>>>(x0, bases, 8192 * 2048 / 4);
    // base0: h32 = silu0 @ base_w0^T
    kan_gemm<128, false, 1><<<g128, 256, 0, stream>>>(
        silu0, base_w0_bf, 2048, 2048, nullptr, nullptr, nullptr, nullptr, nullptr, nullptr, h32);
    // spline0 (plain GEMM now): h = h32 + bases @ spline_w0^T ; emit h_bf + silu1
    kan_gemm<128, false, 2><<<g128, 256, 0, stream>>>(
        bases, spline_w0_bf, 16384, 16384, nullptr, nullptr, nullptr, h_bf, silu1, h32, nullptr);
    // bases of layer-1 x (h)
    basis_gen_kernel<<<2048, 256, 0, stream>>>(h_bf, bases, 8192 * 1024 / 4);
    // base1: out = silu1 @ base_w1^T
    kan_gemm<128, false, 1><<<g128, 256, 0, stream>>>(
        silu1, base_w1_bf, 1024, 1024, nullptr, nullptr, nullptr, nullptr, nullptr, nullptr, out);
    // spline1: out += bases @ spline_w1^T
    kan_gemm<128, false, 3><<<g128, 256, 0, stream>>>(
        bases, spline_w1_bf, 8192, 8192, nullptr, nullptr, nullptr, nullptr, nullptr, out, out);
  } else {
    // ---------- fallback: proven round-3 path (168 MiB) ----------
    u16* attn_w_bf    = (u16*)(ws + 0);
    u16* base_w0_bf   = (u16*)(ws + 4194304);
    u16* spline_w0_bf = (u16*)(ws + 8388608);
    u16* combined     = (u16*)(ws + 41943040);
    u16* h_bf         = combined;
    u16* silu1        = (u16*)(ws + 41943040 + 16777216);
    u16* x0           = (u16*)(ws + 75497472);
    u16* base_w1_bf   = x0;
    u16* spline_w1_bf = (u16*)(ws + 75497472 + 2097152);
    u16* silu0        = (u16*)(ws + 109051904);
    float* h32        = (float*)(ws + 142606336);

    cvt(attn_w, attn_w_bf, 1024 * 2048);
    cvt(base_w0, base_w0_bf, 1024 * 2048);
    cvt(spline_w0, spline_w0_bf, 1024 * 2048 * 8);
    build_combined_kernel<<<16384, 256, 0, stream>>>(feat1, feat2, combined);

    dim3 g256(8192 / 128, 1024 / 256);
    kan_gemm<128, false, 0><<<g128, 256, 0, stream>>>(
        combined, attn_w_bf, 2048, 2048, attn_b, feat1, feat2, x0, silu0, nullptr, nullptr);
    kan_gemm<128, false, 1><<<g128, 256, 0, stream>>>(
        silu0, base_w0_bf, 2048, 2048, nullptr, nullptr, nullptr, nullptr, nullptr, nullptr, h32);
    kan_gemm<256, true, 2><<<g256, 512, 0, stream>>>(
        x0, spline_w0_bf, 16384, 2048, nullptr, nullptr, nullptr, h_bf, silu1, h32, nullptr);
    cvt(base_w1, base_w1_bf, 1024 * 1024);
    cvt(spline_w1, spline_w1_bf, 1024 * 1024 * 8);
    kan_gemm<128, false, 1><<<g128, 256, 0, stream>>>(
        silu1, base_w1_bf, 1024, 1024, nullptr, nullptr, nullptr, nullptr, nullptr, nullptr, out);
    kan_gemm<256, true, 3><<<g256, 512, 0, stream>>>(
        h_bf, spline_w1_bf, 8192, 1024, nullptr, nullptr, nullptr, nullptr, nullptr, out, out);
  }
}

// Round 5
// 1180.660 us; speedup vs baseline: 1.0560x; 1.0543x over previous
//
#include <hip/hip_runtime.h>
#include <hip/hip_bf16.h>
#include <stdint.h>

#define DEVINL __device__ __forceinline__

typedef unsigned short u16;
typedef unsigned int   u32;
typedef unsigned long long u64;

using short8 = __attribute__((ext_vector_type(8))) short;
using f32x4  = __attribute__((ext_vector_type(4))) float;

DEVINL u16 f2bf(float f) {                       // RNE float->bf16
  u32 u = __builtin_bit_cast(u32, f);
  return (u16)((u + 0x7fffu + ((u >> 16) & 1u)) >> 16);
}
DEVINL float bf2f(u16 v) { return __builtin_bit_cast(float, ((u32)v) << 16); }

typedef const unsigned int __attribute__((address_space(1)))* gas1_t;
typedef unsigned int __attribute__((address_space(3)))* las3_t;

DEVINL void gl_lds16(const void* g, void* l) {   // async global->LDS, 16B/lane
  __builtin_amdgcn_global_load_lds((gas1_t)(uintptr_t)g, (las3_t)(uintptr_t)l, 16, 0, 0);
}

// ---- uniform cubic B-spline: 8 bases (bf16) of one x, packed as uint4 ----
DEVINL uint4 bspline8(float xv) {
  float uu = fmaf(xv, 2.5f, 5.5f);               // u = (x + 2.2)/0.4
  float fl = floorf(uu);
  int p = (int)fl;
  float t = uu - fl;
  bool valid = (uu >= 0.0f) && (uu < 11.0f);
  float t2 = t * t, t3 = t2 * t;
  float s1 = 1.0f - t;
  float v0 = t3 * (1.0f / 6.0f);                                          // slot p
  float v1 = fmaf(t3, -0.5f, fmaf(t2, 0.5f, fmaf(t, 0.5f, 1.0f / 6.0f))); // p-1
  float v2 = fmaf(t3, 0.5f, fmaf(t2, -1.0f, 2.0f / 3.0f));                // p-2
  float v3 = s1 * s1 * s1 * (1.0f / 6.0f);                                // p-3
  u64 wp = (u64)f2bf(v3) | ((u64)f2bf(v2) << 16) |
           ((u64)f2bf(v1) << 32) | ((u64)f2bf(v0) << 48);
  if (!valid) wp = 0;
  int pcl = p < 0 ? 0 : (p > 10 ? 10 : p);
  int sb = (pcl << 4) - 48;                      // bit-position of window start
  u32 wd[4];
#pragma unroll
  for (int wi = 0; wi < 4; ++wi) {
    int dd = 32 * wi - sb;
    u32 val = 0;
    if (dd > -32 && dd < 64)
      val = (dd >= 0) ? (u32)(wp >> dd) : (u32)(wp << (-dd));
    wd[wi] = val;
  }
  return make_uint4(wd[0], wd[1], wd[2], wd[3]);
}

// ---------------- elementwise kernels ----------------
__global__ void cvt_bf16_kernel(const float* __restrict__ s, u16* __restrict__ d, int n4) {
  int i = blockIdx.x * 256 + threadIdx.x;
  if (i >= n4) return;
  float4 v = ((const float4*)s)[i];
  u32 lo = (u32)f2bf(v.x) | ((u32)f2bf(v.y) << 16);
  u32 hi = (u32)f2bf(v.z) | ((u32)f2bf(v.w) << 16);
  ((uint2*)d)[i] = make_uint2(lo, hi);
}

__global__ void build_combined_kernel(const float* __restrict__ f1,
                                      const float* __restrict__ f2,
                                      u16* __restrict__ d) {
  int i = blockIdx.x * 256 + threadIdx.x;        // 8192*2048/4 groups, grid exact
  int row = i >> 9, c4 = i & 511;                // 512 float4-groups per row
  const float* s = (c4 < 256) ? (f1 + (size_t)row * 1024 + c4 * 4)
                              : (f2 + (size_t)row * 1024 + (c4 - 256) * 4);
  float4 v = *(const float4*)s;
  u32 lo = (u32)f2bf(v.x) | ((u32)f2bf(v.y) << 16);
  u32 hi = (u32)f2bf(v.z) | ((u32)f2bf(v.w) << 16);
  ((uint2*)d)[i] = make_uint2(lo, hi);
}

// ---------------- fused KAN GEMM ----------------
// C[m,n] = sum_k A[m,k] * W[n,k]   (W row-major N x K, bf16)
// SPLINE: A staged as on-the-fly cubic B-spline bases of x (K = 8 * x_cols)
// EPI: 0=attention(sigmoid+gate+silu outs) 1=store f32 2=add+h/silu(h) bf16 3=add into outf
constexpr int BM = 128, BK = 64;

template <int BN, bool SPLINE, int EPI>
__global__ __launch_bounds__((BN == 256) ? 512 : 256)
void kan_gemm(const u16* __restrict__ Asrc, const u16* __restrict__ Bw,
              int K, int lda,
              const float* __restrict__ bias,
              const float* __restrict__ f1g, const float* __restrict__ f2g,
              u16* __restrict__ o_a, u16* __restrict__ o_b,
              const float* addsrc, float* outf) {
  constexpr int THREADS = (BN == 256) ? 512 : 256;
  constexpr int WN = BN / 64;
  constexpr int AR = (BM * BK) / (THREADS * 8);  // A staging rounds (8 elems = 16B / thread)
  constexpr int BR = (BN * BK) / (THREADS * 8);

  __shared__ __align__(16) u16 As[BM * BK];
  __shared__ __align__(16) u16 Bs[BN * BK];

  const int tid = threadIdx.x;
  const int lane = tid & 63;
  const int wv = tid >> 6;
  const int wm = wv / WN, wn = wv % WN;
  const int l15 = lane & 15, lhi = lane >> 4;
  const int m0 = blockIdx.x * BM, n0 = blockIdx.y * BN;

  f32x4 acc[4][4] = {};

  for (int kt = 0; kt < K; kt += BK) {
    // ---- stage A tile ----
    if constexpr (!SPLINE) {
#pragma unroll
      for (int r = 0; r < AR; ++r) {
        int e = (r * THREADS + tid) * 8;
        int row = e >> 6, col = e & 63;
        gl_lds16(Asrc + (size_t)(m0 + row) * lda + kt + col, &As[e]);
      }
    } else {
      // each thread produces bases for (BM*8)/THREADS x-values (8 bf16 each -> 16B LDS)
#pragma unroll
      for (int s = 0; s < (BM * 8) / THREADS; ++s) {
        int e = tid + s * THREADS;
        int row = e >> 3, xc = e & 7;
        float xv = bf2f(Asrc[(size_t)(m0 + row) * lda + (kt >> 3) + xc]);
        *(uint4*)&As[(row << 6) + (xc << 3)] = bspline8(xv);
      }
    }
    // ---- stage B tile ----
#pragma unroll
    for (int r = 0; r < BR; ++r) {
      int e = (r * THREADS + tid) * 8;
      int row = e >> 6, col = e & 63;
      gl_lds16(Bw + (size_t)(n0 + row) * K + kt + col, &Bs[e]);
    }
    __syncthreads();
    // ---- MFMA ----
#pragma unroll
    for (int ks = 0; ks < BK; ks += 32) {
      short8 av[4], bv[4];
#pragma unroll
      for (int i = 0; i < 4; ++i)
        av[i] = *(const short8*)&As[(wm * 64 + i * 16 + l15) * BK + ks + lhi * 8];
#pragma unroll
      for (int j = 0; j < 4; ++j)
        bv[j] = *(const short8*)&Bs[(wn * 64 + j * 16 + l15) * BK + ks + lhi * 8];
#pragma unroll
      for (int i = 0; i < 4; ++i)
#pragma unroll
        for (int j = 0; j < 4; ++j)
          acc[i][j] = __builtin_amdgcn_mfma_f32_16x16x32_bf16(av[i], bv[j], acc[i][j], 0, 0, 0);
    }
    __syncthreads();
  }

  // ---- epilogue ----  C/D layout: col = lane&15, row = (lane>>4)*4 + reg   [m89/m91]
  const int rbase = m0 + wm * 64 + lhi * 4;
  const int cbase = n0 + wn * 64 + l15;
#pragma unroll
  for (int i = 0; i < 4; ++i) {
#pragma unroll
    for (int r = 0; r < 4; ++r) {
      const int grow = rbase + i * 16 + r;
#pragma unroll
      for (int j = 0; j < 4; ++j) {
        const int gcol = cbase + j * 16;
        float v = acc[i][j][r];
        if constexpr (EPI == 0) {
          float att = 1.0f / (1.0f + __expf(-(v + bias[gcol])));
          float a1 = f1g[(size_t)grow * 1024 + gcol] * att;
          float a2 = f2g[(size_t)grow * 1024 + gcol] * (1.0f - att);
          size_t b0i = (size_t)grow * 2048 + gcol;
          o_a[b0i]        = f2bf(a1);                               // kan_in
          o_a[b0i + 1024] = f2bf(a2);
          o_b[b0i]        = f2bf(a1 / (1.0f + __expf(-a1)));        // silu(kan_in)
          o_b[b0i + 1024] = f2bf(a2 / (1.0f + __expf(-a2)));
        } else if constexpr (EPI == 1) {
          outf[(size_t)grow * 1024 + gcol] = v;
        } else if constexpr (EPI == 2) {
          size_t ix = (size_t)grow * 1024 + gcol;
          float h = v + addsrc[ix];
          o_a[ix] = f2bf(h);                                        // h (bf16)
          o_b[ix] = f2bf(h / (1.0f + __expf(-h)));                  // silu(h)
        } else {
          size_t ix = (size_t)grow * 1024 + gcol;
          outf[ix] = v + addsrc[ix];
        }
      }
    }
  }
}

// ---------------- host launch ----------------
extern "C" void kernel_launch(void* const* d_in, const int* in_sizes, int n_in,
                              void* d_out, int out_size, void* d_ws, size_t ws_size,
                              hipStream_t stream) {
  const float* feat1     = (const float*)d_in[0];
  const float* feat2     = (const float*)d_in[1];
  const float* attn_w    = (const float*)d_in[2];
  const float* attn_b    = (const float*)d_in[3];
  const float* base_w0   = (const float*)d_in[4];
  const float* spline_w0 = (const float*)d_in[5];
  const float* base_w1   = (const float*)d_in[6];
  const float* spline_w1 = (const float*)d_in[7];
  float* out = (float*)d_out;
  char*  ws  = (char*)d_ws;

  // workspace layout (168 MiB total; ws_size is known to be < 442 MiB)
  u16* attn_w_bf    = (u16*)(ws + 0);                       //  4 MiB
  u16* base_w0_bf   = (u16*)(ws + 4194304);                 //  4 MiB
  u16* spline_w0_bf = (u16*)(ws + 8388608);                 // 32 MiB
  u16* combined     = (u16*)(ws + 41943040);                // 32 MiB (reused below)
  u16* h_bf         = combined;                             // 16 MiB (after attn GEMM)
  u16* silu1        = (u16*)(ws + 41943040 + 16777216);     // 16 MiB
  u16* x0           = (u16*)(ws + 75497472);                // 32 MiB (reused below)
  u16* base_w1_bf   = x0;                                   //  2 MiB (after spline0)
  u16* spline_w1_bf = (u16*)(ws + 75497472 + 2097152);      // 16 MiB
  u16* silu0        = (u16*)(ws + 109051904);               // 32 MiB
  float* h32        = (float*)(ws + 142606336);             // 32 MiB

  auto cvt = [&](const float* s, u16* d, int n) {
    int n4 = n >> 2;
    cvt_bf16_kernel<<<(n4 + 255) / 256, 256, 0, stream>>>(s, d, n4);
  };

  cvt(attn_w, attn_w_bf, 1024 * 2048);
  cvt(base_w0, base_w0_bf, 1024 * 2048);
  cvt(spline_w0, spline_w0_bf, 1024 * 2048 * 8);
  build_combined_kernel<<<16384, 256, 0, stream>>>(feat1, feat2, combined);

  dim3 g128(8192 / 128, 1024 / 128);               // 512 blocks = 2 blocks/CU

  // attention = sigmoid(combined @ attn_w^T + b); epilogue emits kan_in + silu(kan_in)
  kan_gemm<128, false, 0><<<g128, 256, 0, stream>>>(
      combined, attn_w_bf, 2048, 2048, attn_b, feat1, feat2, x0, silu0, nullptr, nullptr);
  // base0: h32 = silu0 @ base_w0^T
  kan_gemm<128, false, 1><<<g128, 256, 0, stream>>>(
      silu0, base_w0_bf, 2048, 2048, nullptr, nullptr, nullptr, nullptr, nullptr, nullptr, h32);
  // spline0 (BN=128 now: 512 blocks, 2/CU): h = h32 + bases(x0) @ spline_w0^T ; emit h_bf + silu1
  kan_gemm<128, true, 2><<<g128, 256, 0, stream>>>(
      x0, spline_w0_bf, 16384, 2048, nullptr, nullptr, nullptr, h_bf, silu1, h32, nullptr);
  // layer-1 weights (into dead x0 region)
  cvt(base_w1, base_w1_bf, 1024 * 1024);
  cvt(spline_w1, spline_w1_bf, 1024 * 1024 * 8);
  // base1: out = silu1 @ base_w1^T
  kan_gemm<128, false, 1><<<g128, 256, 0, stream>>>(
      silu1, base_w1_bf, 1024, 1024, nullptr, nullptr, nullptr, nullptr, nullptr, nullptr, out);
  // spline1 (BN=128): out += bases(h_bf) @ spline_w1^T
  kan_gemm<128, true, 3><<<g128, 256, 0, stream>>>(
      h_bf, spline_w1_bf, 8192, 1024, nullptr, nullptr, nullptr, nullptr, nullptr, out, out);
}

// Round 6
// 1108.633 us; speedup vs baseline: 1.1246x; 1.0650x over previous
//
#include <hip/hip_runtime.h>
#include <hip/hip_bf16.h>
#include <stdint.h>

#define DEVINL __device__ __forceinline__

typedef unsigned short u16;
typedef unsigned int   u32;
typedef unsigned long long u64;

using short8 = __attribute__((ext_vector_type(8))) short;
using f32x4  = __attribute__((ext_vector_type(4))) float;

DEVINL u16 f2bf(float f) {                       // RNE float->bf16
  u32 u = __builtin_bit_cast(u32, f);
  return (u16)((u + 0x7fffu + ((u >> 16) & 1u)) >> 16);
}
DEVINL float bf2f(u16 v) { return __builtin_bit_cast(float, ((u32)v) << 16); }

typedef const unsigned int __attribute__((address_space(1)))* gas1_t;
typedef unsigned int __attribute__((address_space(3)))* las3_t;

DEVINL void gl_lds16(const void* g, void* l) {   // async global->LDS, 16B/lane
  __builtin_amdgcn_global_load_lds((gas1_t)(uintptr_t)g, (las3_t)(uintptr_t)l, 16, 0, 0);
}

// ---- uniform cubic B-spline: 8 bases (bf16) of one x, packed as uint4 ----
DEVINL uint4 bspline8(float xv) {
  float uu = fmaf(xv, 2.5f, 5.5f);               // u = (x + 2.2)/0.4
  float fl = floorf(uu);
  int p = (int)fl;
  float t = uu - fl;
  bool valid = (uu >= 0.0f) && (uu < 11.0f);
  float t2 = t * t, t3 = t2 * t;
  float s1 = 1.0f - t;
  float v0 = t3 * (1.0f / 6.0f);                                          // slot p
  float v1 = fmaf(t3, -0.5f, fmaf(t2, 0.5f, fmaf(t, 0.5f, 1.0f / 6.0f))); // p-1
  float v2 = fmaf(t3, 0.5f, fmaf(t2, -1.0f, 2.0f / 3.0f));                // p-2
  float v3 = s1 * s1 * s1 * (1.0f / 6.0f);                                // p-3
  u64 wp = (u64)f2bf(v3) | ((u64)f2bf(v2) << 16) |
           ((u64)f2bf(v1) << 32) | ((u64)f2bf(v0) << 48);
  if (!valid) wp = 0;
  int pcl = p < 0 ? 0 : (p > 10 ? 10 : p);
  int sb = (pcl << 4) - 48;                      // bit-position of window start
  u32 wd[4];
#pragma unroll
  for (int wi = 0; wi < 4; ++wi) {
    int dd = 32 * wi - sb;
    u32 val = 0;
    if (dd > -32 && dd < 64)
      val = (dd >= 0) ? (u32)(wp >> dd) : (u32)(wp << (-dd));
    wd[wi] = val;
  }
  return make_uint4(wd[0], wd[1], wd[2], wd[3]);
}

// ---------------- elementwise kernels ----------------
__global__ void cvt_bf16_kernel(const float* __restrict__ s, u16* __restrict__ d, int n4) {
  int i = blockIdx.x * 256 + threadIdx.x;
  if (i >= n4) return;
  float4 v = ((const float4*)s)[i];
  u32 lo = (u32)f2bf(v.x) | ((u32)f2bf(v.y) << 16);
  u32 hi = (u32)f2bf(v.z) | ((u32)f2bf(v.w) << 16);
  ((uint2*)d)[i] = make_uint2(lo, hi);
}

__global__ void build_combined_kernel(const float* __restrict__ f1,
                                      const float* __restrict__ f2,
                                      u16* __restrict__ d) {
  int i = blockIdx.x * 256 + threadIdx.x;        // 8192*2048/4 groups, grid exact
  int row = i >> 9, c4 = i & 511;                // 512 float4-groups per row
  const float* s = (c4 < 256) ? (f1 + (size_t)row * 1024 + c4 * 4)
                              : (f2 + (size_t)row * 1024 + (c4 - 256) * 4);
  float4 v = *(const float4*)s;
  u32 lo = (u32)f2bf(v.x) | ((u32)f2bf(v.y) << 16);
  u32 hi = (u32)f2bf(v.z) | ((u32)f2bf(v.w) << 16);
  ((uint2*)d)[i] = make_uint2(lo, hi);
}

// ---------------- fused KAN GEMM ----------------
// C[m,n] = sum_k A[m,k] * W[n,k]   (W row-major N x K, bf16)
// SPLINE: A staged as on-the-fly cubic B-spline bases of x (K = 8 * x_cols)
// EPI: 0=attention(sigmoid+gate+silu outs) 1=store f32 2=add+h/silu(h) bf16 3=add into outf
constexpr int BK = 64;

template <int BM, int BN, bool SPLINE, int EPI>
__global__ __launch_bounds__(64 * (BM / 64) * (BN / 64))
void kan_gemm(const u16* __restrict__ Asrc, const u16* __restrict__ Bw,
              int K, int lda,
              const float* __restrict__ bias,
              const float* __restrict__ f1g, const float* __restrict__ f2g,
              u16* __restrict__ o_a, u16* __restrict__ o_b,
              const float* addsrc, float* outf) {
  constexpr int THREADS = 64 * (BM / 64) * (BN / 64);
  constexpr int WN = BN / 64;
  constexpr int AR = (BM * BK) / (THREADS * 8);  // A staging rounds (8 elems = 16B / thread)
  constexpr int BR = (BN * BK) / (THREADS * 8);

  __shared__ __align__(16) u16 As[BM * BK];
  __shared__ __align__(16) u16 Bs[BN * BK];

  const int tid = threadIdx.x;
  const int lane = tid & 63;
  const int wv = tid >> 6;
  const int wm = wv / WN, wn = wv % WN;
  const int l15 = lane & 15, lhi = lane >> 4;
  const int m0 = blockIdx.x * BM, n0 = blockIdx.y * BN;

  f32x4 acc[4][4] = {};

  for (int kt = 0; kt < K; kt += BK) {
    // ---- stage A tile ----
    if constexpr (!SPLINE) {
#pragma unroll
      for (int r = 0; r < AR; ++r) {
        int e = (r * THREADS + tid) * 8;
        int row = e >> 6, col = e & 63;
        gl_lds16(Asrc + (size_t)(m0 + row) * lda + kt + col, &As[e]);
      }
    } else {
      // each thread produces bases for (BM*8)/THREADS x-values (8 bf16 each -> 16B LDS)
#pragma unroll
      for (int s = 0; s < (BM * 8) / THREADS; ++s) {
        int e = tid + s * THREADS;
        int row = e >> 3, xc = e & 7;
        float xv = bf2f(Asrc[(size_t)(m0 + row) * lda + (kt >> 3) + xc]);
        *(uint4*)&As[(row << 6) + (xc << 3)] = bspline8(xv);
      }
    }
    // ---- stage B tile ----
#pragma unroll
    for (int r = 0; r < BR; ++r) {
      int e = (r * THREADS + tid) * 8;
      int row = e >> 6, col = e & 63;
      gl_lds16(Bw + (size_t)(n0 + row) * K + kt + col, &Bs[e]);
    }
    __syncthreads();
    // ---- MFMA ----
#pragma unroll
    for (int ks = 0; ks < BK; ks += 32) {
      short8 av[4], bv[4];
#pragma unroll
      for (int i = 0; i < 4; ++i)
        av[i] = *(const short8*)&As[(wm * 64 + i * 16 + l15) * BK + ks + lhi * 8];
#pragma unroll
      for (int j = 0; j < 4; ++j)
        bv[j] = *(const short8*)&Bs[(wn * 64 + j * 16 + l15) * BK + ks + lhi * 8];
#pragma unroll
      for (int i = 0; i < 4; ++i)
#pragma unroll
        for (int j = 0; j < 4; ++j)
          acc[i][j] = __builtin_amdgcn_mfma_f32_16x16x32_bf16(av[i], bv[j], acc[i][j], 0, 0, 0);
    }
    __syncthreads();
  }

  // ---- epilogue ----  C/D layout: col = lane&15, row = (lane>>4)*4 + reg   [m89/m91]
  const int rbase = m0 + wm * 64 + lhi * 4;
  const int cbase = n0 + wn * 64 + l15;
#pragma unroll
  for (int i = 0; i < 4; ++i) {
#pragma unroll
    for (int r = 0; r < 4; ++r) {
      const int grow = rbase + i * 16 + r;
#pragma unroll
      for (int j = 0; j < 4; ++j) {
        const int gcol = cbase + j * 16;
        float v = acc[i][j][r];
        if constexpr (EPI == 0) {
          float att = 1.0f / (1.0f + __expf(-(v + bias[gcol])));
          float a1 = f1g[(size_t)grow * 1024 + gcol] * att;
          float a2 = f2g[(size_t)grow * 1024 + gcol] * (1.0f - att);
          size_t b0i = (size_t)grow * 2048 + gcol;
          o_a[b0i]        = f2bf(a1);                               // kan_in
          o_a[b0i + 1024] = f2bf(a2);
          o_b[b0i]        = f2bf(a1 / (1.0f + __expf(-a1)));        // silu(kan_in)
          o_b[b0i + 1024] = f2bf(a2 / (1.0f + __expf(-a2)));
        } else if constexpr (EPI == 1) {
          outf[(size_t)grow * 1024 + gcol] = v;
        } else if constexpr (EPI == 2) {
          size_t ix = (size_t)grow * 1024 + gcol;
          float h = v + addsrc[ix];
          o_a[ix] = f2bf(h);                                        // h (bf16)
          o_b[ix] = f2bf(h / (1.0f + __expf(-h)));                  // silu(h)
        } else {
          size_t ix = (size_t)grow * 1024 + gcol;
          outf[ix] = v + addsrc[ix];
        }
      }
    }
  }
}

// ---------------- host launch ----------------
extern "C" void kernel_launch(void* const* d_in, const int* in_sizes, int n_in,
                              void* d_out, int out_size, void* d_ws, size_t ws_size,
                              hipStream_t stream) {
  const float* feat1     = (const float*)d_in[0];
  const float* feat2     = (const float*)d_in[1];
  const float* attn_w    = (const float*)d_in[2];
  const float* attn_b    = (const float*)d_in[3];
  const float* base_w0   = (const float*)d_in[4];
  const float* spline_w0 = (const float*)d_in[5];
  const float* base_w1   = (const float*)d_in[6];
  const float* spline_w1 = (const float*)d_in[7];
  float* out = (float*)d_out;
  char*  ws  = (char*)d_ws;

  // workspace layout (168 MiB total)
  u16* attn_w_bf    = (u16*)(ws + 0);                       //  4 MiB
  u16* base_w0_bf   = (u16*)(ws + 4194304);                 //  4 MiB
  u16* spline_w0_bf = (u16*)(ws + 8388608);                 // 32 MiB
  u16* combined     = (u16*)(ws + 41943040);                // 32 MiB (reused below)
  u16* h_bf         = combined;                             // 16 MiB (after attn GEMM)
  u16* silu1        = (u16*)(ws + 41943040 + 16777216);     // 16 MiB
  u16* x0           = (u16*)(ws + 75497472);                // 32 MiB (reused below)
  u16* base_w1_bf   = x0;                                   //  2 MiB (after spline0)
  u16* spline_w1_bf = (u16*)(ws + 75497472 + 2097152);      // 16 MiB
  u16* silu0        = (u16*)(ws + 109051904);               // 32 MiB
  float* h32        = (float*)(ws + 142606336);             // 32 MiB

  auto cvt = [&](const float* s, u16* d, int n) {
    int n4 = n >> 2;
    cvt_bf16_kernel<<<(n4 + 255) / 256, 256, 0, stream>>>(s, d, n4);
  };

  cvt(attn_w, attn_w_bf, 1024 * 2048);
  cvt(base_w0, base_w0_bf, 1024 * 2048);
  cvt(spline_w0, spline_w0_bf, 1024 * 2048 * 8);
  build_combined_kernel<<<16384, 256, 0, stream>>>(feat1, feat2, combined);

  dim3 g128(8192 / 128, 1024 / 128);               // 512 blocks = 2 blocks/CU
  dim3 gsp(8192 / 64, 1024 / 256);                 // 512 blocks = 2 blocks/CU, 4 N-panels

  // attention = sigmoid(combined @ attn_w^T + b); epilogue emits kan_in + silu(kan_in)
  kan_gemm<128, 128, false, 0><<<g128, 256, 0, stream>>>(
      combined, attn_w_bf, 2048, 2048, attn_b, feat1, feat2, x0, silu0, nullptr, nullptr);
  // base0: h32 = silu0 @ base_w0^T
  kan_gemm<128, 128, false, 1><<<g128, 256, 0, stream>>>(
      silu0, base_w0_bf, 2048, 2048, nullptr, nullptr, nullptr, nullptr, nullptr, nullptr, h32);
  // spline0 (64x256 tile: half the basis redundancy): h = h32 + bases(x0) @ spline_w0^T
  kan_gemm<64, 256, true, 2><<<gsp, 256, 0, stream>>>(
      x0, spline_w0_bf, 16384, 2048, nullptr, nullptr, nullptr, h_bf, silu1, h32, nullptr);
  // layer-1 weights (into dead x0 region)
  cvt(base_w1, base_w1_bf, 1024 * 1024);
  cvt(spline_w1, spline_w1_bf, 1024 * 1024 * 8);
  // base1: out = silu1 @ base_w1^T
  kan_gemm<128, 128, false, 1><<<g128, 256, 0, stream>>>(
      silu1, base_w1_bf, 1024, 1024, nullptr, nullptr, nullptr, nullptr, nullptr, nullptr, out);
  // spline1 (64x256): out += bases(h_bf) @ spline_w1^T
  kan_gemm<64, 256, true, 3><<<gsp, 256, 0, stream>>>(
      h_bf, spline_w1_bf, 8192, 1024, nullptr, nullptr, nullptr, nullptr, nullptr, out, out);
}